// Round 4
// baseline (1448.615 us; speedup 1.0000x reference)
//
#include <hip/hip_runtime.h>
#include <hip/hip_bf16.h>

typedef __attribute__((ext_vector_type(4))) float f32x4;
typedef __attribute__((ext_vector_type(4))) int   i32x4;
typedef __attribute__((ext_vector_type(8))) short s16x8;
typedef unsigned short ushort_t;

#define MDIM 8192
#define KDIM 4096
#define NDIM 16384
#define NKT  (KDIM / 32)        // 128 K-tiles of BK=32

static __device__ __forceinline__ short f2bf(float f) {
    __bf16 h = (__bf16)f;
    return __builtin_bit_cast(short, h);
}

static __device__ __forceinline__ void gload_lds16(const void* g, void* l) {
    __builtin_amdgcn_global_load_lds(
        (const __attribute__((address_space(1))) unsigned int*)g,
        (__attribute__((address_space(3))) unsigned int*)l,
        16, 0, 0);
}

// ---------------- convert kernels (memory-bound, vectorized) ----------------

__global__ __launch_bounds__(256)
void cvt_f32_bf16(const float* __restrict__ in, ushort_t* __restrict__ out, int n8) {
    for (int i = blockIdx.x * blockDim.x + threadIdx.x; i < n8;
         i += gridDim.x * blockDim.x) {
        f32x4 a = ((const f32x4*)in)[i * 2];
        f32x4 b = ((const f32x4*)in)[i * 2 + 1];
        s16x8 o;
        #pragma unroll
        for (int q = 0; q < 4; ++q) o[q] = f2bf(a[q]);
        #pragma unroll
        for (int q = 0; q < 4; ++q) o[4 + q] = f2bf(b[q]);
        ((s16x8*)out)[i] = o;
    }
}

__global__ __launch_bounds__(256)
void cvt_i32_bf16(const int* __restrict__ in, ushort_t* __restrict__ out, int n8) {
    for (int i = blockIdx.x * blockDim.x + threadIdx.x; i < n8;
         i += gridDim.x * blockDim.x) {
        i32x4 a = ((const i32x4*)in)[i * 2];
        i32x4 b = ((const i32x4*)in)[i * 2 + 1];
        s16x8 o;
        #pragma unroll
        for (int q = 0; q < 4; ++q) o[q] = f2bf((float)a[q]);   // |v|<=127: exact
        #pragma unroll
        for (int q = 0; q < 4; ++q) o[4 + q] = f2bf((float)b[q]);
        ((s16x8*)out)[i] = o;
    }
}

// ---------------- 256x256 bf16 GEMM, ring-4 LDS, minimal sync --------------
// C[m][n] = sum_k A[m][k]*B[n][k], BK=32, ring of 4 LDS K-tile buffers.
// Per iteration it: stage buf (it+2)&3 via global_load_lds, ds_read+MFMA on
// buf it&3, then ONE {vmcnt(4); s_barrier; sched_barrier(0)} boundary.
// vmcnt(4) leaves only this iteration's own 4 staging loads outstanding ->
// every older load (incl. buf it+1's data) has landed; the barrier publishes
// that across waves. No intra-iteration barriers: compiler + wave drift
// overlap LDS reads with MFMA and staging.
// Rows are 64 B = 4 slots of 16 B; physical slot = logical ^ ((row>>1)&3);
// swizzle applied on the GLOBAL source address, LDS dest stays linear.

__global__ __launch_bounds__(512, 2)
void sl_gemm_256(const ushort_t* __restrict__ A, const ushort_t* __restrict__ Bw,
                 const float* __restrict__ scale_p, const float* __restrict__ bias,
                 float* __restrict__ Out)
{
    __shared__ char lds[131072];   // 4 bufs x (A 16 KB + B 16 KB)

    const int t    = threadIdx.x;
    const int lane = t & 63;
    const int wave = t >> 6;        // 0..7
    const int wr   = wave >> 2;     // 0..1 : 128 output rows each
    const int wc   = wave & 3;      // 0..3 : 64  output cols each

    // ---- tile mapping: XCD chunks of 256, then 16-tn panels, tm fastest
    int bid = blockIdx.x;                       // 2048 blocks (32 tm x 64 tn)
    int swz = (bid & 7) * 256 + (bid >> 3);
    int panel = swz >> 9;                       // 4 panels of 32tm x 16tn
    int inp   = swz & 511;
    int tn = (panel << 4) + (inp >> 5);
    int tm = inp & 31;
    const int m0 = tm << 8;
    const int n0 = tn << 8;

    // ---- staging geometry: thread covers row (wave*16 + lane>>2) of a
    //      128-row chunk, physical slot lane&3
    const int srow  = wave * 16 + (lane >> 2);            // 0..127
    const int sslot = lane & 3;
    const int sA    = sslot ^ ((srow >> 1) & 3);          // logical slot
    const ushort_t* pA0 = A  + (size_t)(m0 + srow) * KDIM + sA * 8;
    const ushort_t* pA1 = pA0 + (size_t)128 * KDIM;
    const ushort_t* pB0 = Bw + (size_t)(n0 + srow) * KDIM + sA * 8;
    const ushort_t* pB1 = pB0 + (size_t)128 * KDIM;
    const int ldsw = wave * 1024;                          // wave-uniform dest

    // ---- fragment read offsets (byte, buf-relative)
    const int fr = lane & 15;
    const int fs = lane >> 4;                              // 0..3
    int aoff[8], boff[4];
    #pragma unroll
    for (int i = 0; i < 8; ++i) {
        int ra = wr * 128 + i * 16 + fr;
        aoff[i] = ra * 64 + ((fs ^ ((ra >> 1) & 3)) * 16);
    }
    #pragma unroll
    for (int j = 0; j < 4; ++j) {
        int rb = wc * 64 + j * 16 + fr;
        boff[j] = 16384 + rb * 64 + ((fs ^ ((rb >> 1) & 3)) * 16);
    }

    f32x4 acc[8][4];
    #pragma unroll
    for (int i = 0; i < 8; ++i)
        #pragma unroll
        for (int j = 0; j < 4; ++j)
            acc[i][j] = (f32x4){0.f, 0.f, 0.f, 0.f};

    // ---- prologue: stage ktile0 -> buf0, ktile1 -> buf1
    #pragma unroll
    for (int kt = 0; kt < 2; ++kt) {
        const size_t ko  = (size_t)kt * 32;
        char* b = lds + kt * 32768;
        gload_lds16(pA0 + ko, b + ldsw);
        gload_lds16(pA1 + ko, b + 8192  + ldsw);
        gload_lds16(pB0 + ko, b + 16384 + ldsw);
        gload_lds16(pB1 + ko, b + 24576 + ldsw);
    }
    asm volatile("s_waitcnt vmcnt(4)" ::: "memory");   // ktile0 landed
    __builtin_amdgcn_s_barrier();
    __builtin_amdgcn_sched_barrier(0);

    for (int it = 0; it < NKT; ++it) {
        const char* rb = lds + (it & 3) * 32768;
        char*       wb = lds + ((it + 2) & 3) * 32768;
        int kq = it + 2; if (kq >= NKT) kq -= NKT;     // wraparound staging
        const size_t ko = (size_t)kq * 32;

        // stage K-tile it+2 (async; lands before the barrier at end of it+1)
        gload_lds16(pA0 + ko, wb + ldsw);
        gload_lds16(pA1 + ko, wb + 8192  + ldsw);
        gload_lds16(pB0 + ko, wb + 16384 + ldsw);
        gload_lds16(pB1 + ko, wb + 24576 + ldsw);

        // fragments + 32 MFMA, freely compiler-scheduled (fine lgkmcnt)
        s16x8 af[8], bq[4];
        #pragma unroll
        for (int i = 0; i < 8; ++i)
            af[i] = *(const s16x8*)(rb + aoff[i]);
        #pragma unroll
        for (int j = 0; j < 4; ++j)
            bq[j] = *(const s16x8*)(rb + boff[j]);

        #pragma unroll
        for (int i = 0; i < 8; ++i)
            #pragma unroll
            for (int j = 0; j < 4; ++j)
                acc[i][j] = __builtin_amdgcn_mfma_f32_16x16x32_bf16(
                    af[i], bq[j], acc[i][j], 0, 0, 0);

        // single iteration boundary: own 4 loads may stay in flight
        asm volatile("s_waitcnt vmcnt(4)" ::: "memory");
        __builtin_amdgcn_s_barrier();
        __builtin_amdgcn_sched_barrier(0);
    }

    // ---- epilogue: D col = lane&15, row = fs*4 + q; scale + bias
    const float scale = scale_p[0];
    #pragma unroll
    for (int j = 0; j < 4; ++j) {
        const int c   = n0 + wc * 64 + j * 16 + fr;
        const float bj = bias[c];
        #pragma unroll
        for (int i = 0; i < 8; ++i) {
            const int r0 = m0 + wr * 128 + i * 16 + fs * 4;
            float* op = Out + (size_t)r0 * NDIM + c;
            #pragma unroll
            for (int q = 0; q < 4; ++q)
                op[(size_t)q * NDIM] = acc[i][j][q] * scale + bj;
        }
    }
}

// ---------------- fallback (fp32 direct, no workspace) ----------------

__global__ __launch_bounds__(256, 2)
void sl_gemm_fb(const float* __restrict__ X, const int* __restrict__ Wq,
                const float* __restrict__ scale_p, const float* __restrict__ bias,
                float* __restrict__ Out)
{
    __shared__ s16x8 As[128 * 4];
    __shared__ s16x8 Bs[128 * 4];

    const int t    = threadIdx.x;
    const int lane = t & 63;
    const int wave = t >> 6;
    const int wr   = wave >> 1;
    const int wc   = wave & 1;

    int bid = blockIdx.x;
    int swz = (bid & 7) * 1024 + (bid >> 3);
    int panel   = swz >> 10;
    int inpanel = swz & 1023;
    int tn = (panel << 4) + (inpanel >> 6);
    int tm = inpanel & 63;
    const int m0 = tm << 7;
    const int n0 = tn << 7;

    const int srow  = t >> 1;
    const int shalf = t & 1;
    const float* Xp = X  + (size_t)(m0 + srow) * KDIM + shalf * 16;
    const int*   Wp = Wq + (size_t)(n0 + srow) * KDIM + shalf * 16;

    f32x4 acc[4][4];
    #pragma unroll
    for (int i = 0; i < 4; ++i)
        #pragma unroll
        for (int j = 0; j < 4; ++j)
            acc[i][j] = (f32x4){0.f, 0.f, 0.f, 0.f};

    const int fr = lane & 15;
    const int fs = lane >> 4;

    f32x4 ar[4];
    i32x4 br[4];
    #pragma unroll
    for (int p = 0; p < 4; ++p) {
        ar[p] = *(const f32x4*)(Xp + p * 4);
        br[p] = *(const i32x4*)(Wp + p * 4);
    }

    const int wbase = srow * 4;
    const int wswz  = (srow >> 1) & 3;
    const int ws0   = (shalf * 2)     ^ wswz;
    const int ws1   = (shalf * 2 + 1) ^ wswz;

    for (int kt = 0; kt < KDIM / 32; ++kt) {
        __syncthreads();
        {
            s16x8 v0, v1;
            #pragma unroll
            for (int q = 0; q < 8; ++q) v0[q] = f2bf(ar[q >> 2][q & 3]);
            #pragma unroll
            for (int q = 0; q < 8; ++q) v1[q] = f2bf(ar[2 + (q >> 2)][q & 3]);
            As[wbase + ws0] = v0;
            As[wbase + ws1] = v1;
            s16x8 u0, u1;
            #pragma unroll
            for (int q = 0; q < 8; ++q) u0[q] = f2bf((float)br[q >> 2][q & 3]);
            #pragma unroll
            for (int q = 0; q < 8; ++q) u1[q] = f2bf((float)br[2 + (q >> 2)][q & 3]);
            Bs[wbase + ws0] = u0;
            Bs[wbase + ws1] = u1;
        }
        __syncthreads();

        if (kt + 1 < KDIM / 32) {
            const float* Xn = Xp + (size_t)(kt + 1) * 32;
            const int*   Wn = Wp + (size_t)(kt + 1) * 32;
            #pragma unroll
            for (int p = 0; p < 4; ++p) {
                ar[p] = *(const f32x4*)(Xn + p * 4);
                br[p] = *(const i32x4*)(Wn + p * 4);
            }
        }

        s16x8 af[4], bq[4];
        #pragma unroll
        for (int i = 0; i < 4; ++i) {
            int row = wr * 64 + i * 16 + fr;
            af[i] = As[row * 4 + (fs ^ ((row >> 1) & 3))];
        }
        #pragma unroll
        for (int j = 0; j < 4; ++j) {
            int col = wc * 64 + j * 16 + fr;
            bq[j] = Bs[col * 4 + (fs ^ ((col >> 1) & 3))];
        }
        #pragma unroll
        for (int i = 0; i < 4; ++i)
            #pragma unroll
            for (int j = 0; j < 4; ++j)
                acc[i][j] = __builtin_amdgcn_mfma_f32_16x16x32_bf16(
                    af[i], bq[j], acc[i][j], 0, 0, 0);
    }

    const float scale = scale_p[0];
    #pragma unroll
    for (int j = 0; j < 4; ++j) {
        const int c  = n0 + wc * 64 + j * 16 + fr;
        const float bj = bias[c];
        #pragma unroll
        for (int i = 0; i < 4; ++i) {
            const int r0 = m0 + wr * 64 + i * 16 + fs * 4;
            float* op = Out + (size_t)r0 * NDIM + c;
            #pragma unroll
            for (int q = 0; q < 4; ++q)
                op[(size_t)q * NDIM] = acc[i][j][q] * scale + bj;
        }
    }
}

extern "C" void kernel_launch(void* const* d_in, const int* in_sizes, int n_in,
                              void* d_out, int out_size, void* d_ws, size_t ws_size,
                              hipStream_t stream) {
    const float* X     = (const float*)d_in[0];
    const int*   Wq    = (const int*)d_in[1];   // int8 widened to int32 by harness
    const float* scale = (const float*)d_in[2];
    const float* bias  = (const float*)d_in[3];
    float*       Out   = (float*)d_out;

    const size_t xBytes = (size_t)MDIM * KDIM * 2;          // 67 MB
    const size_t wBytes = (size_t)NDIM * KDIM * 2;          // 134 MB
    if (ws_size >= xBytes + wBytes) {
        ushort_t* Xbf = (ushort_t*)d_ws;
        ushort_t* Wbf = (ushort_t*)((char*)d_ws + xBytes);
        hipLaunchKernelGGL(cvt_f32_bf16, dim3(2048), dim3(256), 0, stream,
                           X, Xbf, MDIM * KDIM / 8);
        hipLaunchKernelGGL(cvt_i32_bf16, dim3(2048), dim3(256), 0, stream,
                           Wq, Wbf, NDIM * KDIM / 8);
        hipLaunchKernelGGL(sl_gemm_256, dim3(2048), dim3(512), 0, stream,
                           Xbf, Wbf, scale, bias, Out);
    } else {
        hipLaunchKernelGGL(sl_gemm_fb, dim3(8192), dim3(256), 0, stream,
                           X, Wq, scale, bias, Out);
    }
}

// Round 6
// 1275.848 us; speedup vs baseline: 1.1354x; 1.1354x over previous
//
#include <hip/hip_runtime.h>
#include <hip/hip_bf16.h>

typedef __attribute__((ext_vector_type(4))) float f32x4;
typedef __attribute__((ext_vector_type(4))) int   i32x4;
typedef __attribute__((ext_vector_type(8))) short s16x8;
typedef unsigned short ushort_t;

#define MDIM 8192
#define KDIM 4096
#define NDIM 16384
#define NKT  (KDIM / 32)        // 128 K-tiles of BK=32

static __device__ __forceinline__ short f2bf(float f) {
    __bf16 h = (__bf16)f;
    return __builtin_bit_cast(short, h);
}

static __device__ __forceinline__ void gload_lds16(const void* g, void* l) {
    __builtin_amdgcn_global_load_lds(
        (const __attribute__((address_space(1))) unsigned int*)g,
        (__attribute__((address_space(3))) unsigned int*)l,
        16, 0, 0);
}

// ---------------- convert kernels (memory-bound, vectorized) ----------------

__global__ __launch_bounds__(256)
void cvt_f32_bf16(const float* __restrict__ in, ushort_t* __restrict__ out, int n8) {
    for (int i = blockIdx.x * blockDim.x + threadIdx.x; i < n8;
         i += gridDim.x * blockDim.x) {
        f32x4 a = ((const f32x4*)in)[i * 2];
        f32x4 b = ((const f32x4*)in)[i * 2 + 1];
        s16x8 o;
        #pragma unroll
        for (int q = 0; q < 4; ++q) o[q] = f2bf(a[q]);
        #pragma unroll
        for (int q = 0; q < 4; ++q) o[4 + q] = f2bf(b[q]);
        ((s16x8*)out)[i] = o;
    }
}

__global__ __launch_bounds__(256)
void cvt_i32_bf16(const int* __restrict__ in, ushort_t* __restrict__ out, int n8) {
    for (int i = blockIdx.x * blockDim.x + threadIdx.x; i < n8;
         i += gridDim.x * blockDim.x) {
        i32x4 a = ((const i32x4*)in)[i * 2];
        i32x4 b = ((const i32x4*)in)[i * 2 + 1];
        s16x8 o;
        #pragma unroll
        for (int q = 0; q < 4; ++q) o[q] = f2bf((float)a[q]);   // |v|<=127: exact
        #pragma unroll
        for (int q = 0; q < 4; ++q) o[4 + q] = f2bf((float)b[q]);
        ((s16x8*)out)[i] = o;
    }
}

// ---------------- 256x256 bf16 GEMM, ring-4 LDS, cross-tile reg dbuf -------
// C[m][n] = sum_k A[m][k]*B[n][k], BK=32, ring of 4 LDS K-tile buffers.
// Buffer roles at iteration it:
//   buf (it)&3   : holds tile it   -> already consumed into R_cur last iter
//   buf (it+1)&3 : holds tile it+1 -> 12 ds_reads into R_next this iter
//   buf (it+2)&3 : being filled by iter it-1's staging (drained at our vmcnt)
//   buf (it+3)&3 (== it-1): overwritten by THIS iter's staging (tile it+3);
//     its last readers (iter it-2's R_next reads) drained before iter it-1's
//     first MFMA, hence before the trailing barrier we just passed (barrier
//     collectiveness => all waves). WAR-safe.
// Sync per K-tile: trailing {vmcnt(4); s_barrier; sched_barrier(0)} only.
// vmcnt(4) leaves this iter's own 4 staging loads in flight, drains iter
// it-1's loads -> buf (it+2) published for iter it+1's reads. MFMAs depend
// only on R_cur (loaded last iter) -> no post-barrier LDS-latency stall.
// Rows are 64 B = 4 slots of 16 B; phys slot = logical ^ ((row>>1)&3);
// swizzle applied on the GLOBAL source address, LDS dest stays linear.

#define BAR()   __builtin_amdgcn_s_barrier()
#define SB0()   __builtin_amdgcn_sched_barrier(0)
#define PRIO(N) __builtin_amdgcn_s_setprio(N)

// one K-tile: MFMAs on CUR regs, ds_reads into NXT regs, stage tile IT+3
#define KTILE(CA, CB, NA, NB, IT)                                              \
  {                                                                            \
    const char*  rbuf = ldsc + (((IT) + 1) & 3) * 32768;                       \
    char*        wbuf = ldsc + (((IT) + 3) & 3) * 32768;                       \
    const size_t ko   = (size_t)(((IT) + 3) & (NKT - 1)) * 32;                 \
    /* ---- half 1: issue B+A0..3 reads, stage A units, 16 MFMA ---- */       \
    _Pragma("unroll")                                                          \
    for (int j = 0; j < 4; ++j) NB[j] = *(const s16x8*)(rbuf + boff[j]);       \
    _Pragma("unroll")                                                          \
    for (int i = 0; i < 4; ++i) NA[i] = *(const s16x8*)(rbuf + aoff[i]);       \
    gload_lds16(pA0 + ko, wbuf + ldsw);                                        \
    gload_lds16(pA1 + ko, wbuf + 8192 + ldsw);                                 \
    SB0();                                                                     \
    PRIO(1);                                                                   \
    _Pragma("unroll")                                                          \
    for (int m = 0; m < 4; ++m)                                                \
      _Pragma("unroll")                                                        \
      for (int nn = 0; nn < 4; ++nn)                                           \
        acc[m][nn] = __builtin_amdgcn_mfma_f32_16x16x32_bf16(                  \
            CA[m], CB[nn], acc[m][nn], 0, 0, 0);                               \
    PRIO(0);                                                                   \
    /* ---- half 2: issue A4..7 reads, stage B units, 16 MFMA ---- */          \
    _Pragma("unroll")                                                          \
    for (int i = 4; i < 8; ++i) NA[i] = *(const s16x8*)(rbuf + aoff[i]);       \
    gload_lds16(pB0 + ko, wbuf + 16384 + ldsw);                                \
    gload_lds16(pB1 + ko, wbuf + 24576 + ldsw);                                \
    SB0();                                                                     \
    PRIO(1);                                                                   \
    _Pragma("unroll")                                                          \
    for (int m = 4; m < 8; ++m)                                                \
      _Pragma("unroll")                                                        \
      for (int nn = 0; nn < 4; ++nn)                                           \
        acc[m][nn] = __builtin_amdgcn_mfma_f32_16x16x32_bf16(                  \
            CA[m], CB[nn], acc[m][nn], 0, 0, 0);                               \
    PRIO(0);                                                                   \
    asm volatile("s_waitcnt vmcnt(4)" ::: "memory");                           \
    BAR();                                                                     \
    SB0();                                                                     \
  }

__global__ __launch_bounds__(512, 2)
void sl_gemm_256r(const ushort_t* __restrict__ A, const ushort_t* __restrict__ Bw,
                  const float* __restrict__ scale_p, const float* __restrict__ bias,
                  float* __restrict__ Out)
{
    __shared__ char ldsbuf[131072];   // 4 bufs x (A 16 KB + B 16 KB)
    char* ldsc = ldsbuf;

    const int t    = threadIdx.x;
    const int lane = t & 63;
    const int wave = t >> 6;        // 0..7
    const int wr   = wave >> 2;     // 0..1 : 128 output rows each
    const int wc   = wave & 3;      // 0..3 : 64  output cols each

    // ---- tile mapping: XCD chunks of 256, then 16-tn panels, tm fastest
    int bid = blockIdx.x;                       // 2048 blocks (32 tm x 64 tn)
    int swz = (bid & 7) * 256 + (bid >> 3);
    int panel = swz >> 9, inp = swz & 511;
    int tn = (panel << 4) + (inp >> 5);
    int tm = inp & 31;
    const int m0 = tm << 8;
    const int n0 = tn << 8;

    // ---- staging geometry (verbatim R4, verified): thread covers row
    //      (wave*16 + lane>>2) of a 128-row chunk, physical slot lane&3
    const int srow  = wave * 16 + (lane >> 2);            // 0..127
    const int sslot = lane & 3;
    const int sA    = sslot ^ ((srow >> 1) & 3);          // logical slot
    const ushort_t* pA0 = A  + (size_t)(m0 + srow) * KDIM + sA * 8;
    const ushort_t* pA1 = pA0 + (size_t)128 * KDIM;
    const ushort_t* pB0 = Bw + (size_t)(n0 + srow) * KDIM + sA * 8;
    const ushort_t* pB1 = pB0 + (size_t)128 * KDIM;
    const int ldsw = wave * 1024;                          // wave-uniform dest

    // ---- fragment read offsets (byte, buf-relative; verbatim R4)
    const int fr = lane & 15;
    const int fs = lane >> 4;                              // 0..3
    int aoff[8], boff[4];
    #pragma unroll
    for (int i = 0; i < 8; ++i) {
        int ra = wr * 128 + i * 16 + fr;
        aoff[i] = ra * 64 + ((fs ^ ((ra >> 1) & 3)) * 16);
    }
    #pragma unroll
    for (int j = 0; j < 4; ++j) {
        int rb = wc * 64 + j * 16 + fr;
        boff[j] = 16384 + rb * 64 + ((fs ^ ((rb >> 1) & 3)) * 16);
    }

    f32x4 acc[8][4];
    #pragma unroll
    for (int i = 0; i < 8; ++i)
        #pragma unroll
        for (int j = 0; j < 4; ++j)
            acc[i][j] = (f32x4){0.f, 0.f, 0.f, 0.f};

    // ---- prologue: stage tiles 0,1,2 -> bufs 0,1,2
    #pragma unroll
    for (int kt = 0; kt < 3; ++kt) {
        const size_t ko = (size_t)kt * 32;
        char* b = ldsc + kt * 32768;
        gload_lds16(pA0 + ko, b + ldsw);
        gload_lds16(pA1 + ko, b + 8192  + ldsw);
        gload_lds16(pB0 + ko, b + 16384 + ldsw);
        gload_lds16(pB1 + ko, b + 24576 + ldsw);
    }
    asm volatile("s_waitcnt vmcnt(4)" ::: "memory");   // tiles 0,1 landed
    BAR();
    SB0();

    // R_cur <- tile 0 fragments (buf 0)
    s16x8 FA[8], FB[4], GA[8], GB[4];
    #pragma unroll
    for (int i = 0; i < 8; ++i) FA[i] = *(const s16x8*)(ldsc + aoff[i]);
    #pragma unroll
    for (int j = 0; j < 4; ++j) FB[j] = *(const s16x8*)(ldsc + boff[j]);

    for (int it = 0; it < NKT; it += 2) {
        KTILE(FA, FB, GA, GB, it);
        KTILE(GA, GB, FA, FB, it + 1);
    }

    // ---- epilogue: D col = lane&15, row = fs*4 + q; scale + bias
    const float scale = scale_p[0];
    #pragma unroll
    for (int j = 0; j < 4; ++j) {
        const int c   = n0 + wc * 64 + j * 16 + fr;
        const float bj = bias[c];
        #pragma unroll
        for (int i = 0; i < 8; ++i) {
            const int r0 = m0 + wr * 128 + i * 16 + fs * 4;
            float* op = Out + (size_t)r0 * NDIM + c;
            #pragma unroll
            for (int q = 0; q < 4; ++q)
                op[(size_t)q * NDIM] = acc[i][j][q] * scale + bj;
        }
    }
}

// ---------------- fallback (fp32 direct, no workspace) ----------------

__global__ __launch_bounds__(256, 2)
void sl_gemm_fb(const float* __restrict__ X, const int* __restrict__ Wq,
                const float* __restrict__ scale_p, const float* __restrict__ bias,
                float* __restrict__ Out)
{
    __shared__ s16x8 As[128 * 4];
    __shared__ s16x8 Bs[128 * 4];

    const int t    = threadIdx.x;
    const int lane = t & 63;
    const int wave = t >> 6;
    const int wr   = wave >> 1;
    const int wc   = wave & 1;

    int bid = blockIdx.x;
    int swz = (bid & 7) * 1024 + (bid >> 3);
    int panel   = swz >> 10;
    int inpanel = swz & 1023;
    int tn = (panel << 4) + (inpanel >> 6);
    int tm = inpanel & 63;
    const int m0 = tm << 7;
    const int n0 = tn << 7;

    const int srow  = t >> 1;
    const int shalf = t & 1;
    const float* Xp = X  + (size_t)(m0 + srow) * KDIM + shalf * 16;
    const int*   Wp = Wq + (size_t)(n0 + srow) * KDIM + shalf * 16;

    f32x4 acc[4][4];
    #pragma unroll
    for (int i = 0; i < 4; ++i)
        #pragma unroll
        for (int j = 0; j < 4; ++j)
            acc[i][j] = (f32x4){0.f, 0.f, 0.f, 0.f};

    const int fr = lane & 15;
    const int fs = lane >> 4;

    f32x4 ar[4];
    i32x4 br[4];
    #pragma unroll
    for (int p = 0; p < 4; ++p) {
        ar[p] = *(const f32x4*)(Xp + p * 4);
        br[p] = *(const i32x4*)(Wp + p * 4);
    }

    const int wbase = srow * 4;
    const int wswz  = (srow >> 1) & 3;
    const int ws0   = (shalf * 2)     ^ wswz;
    const int ws1   = (shalf * 2 + 1) ^ wswz;

    for (int kt = 0; kt < KDIM / 32; ++kt) {
        __syncthreads();
        {
            s16x8 v0, v1;
            #pragma unroll
            for (int q = 0; q < 8; ++q) v0[q] = f2bf(ar[q >> 2][q & 3]);
            #pragma unroll
            for (int q = 0; q < 8; ++q) v1[q] = f2bf(ar[2 + (q >> 2)][q & 3]);
            As[wbase + ws0] = v0;
            As[wbase + ws1] = v1;
            s16x8 u0, u1;
            #pragma unroll
            for (int q = 0; q < 8; ++q) u0[q] = f2bf((float)br[q >> 2][q & 3]);
            #pragma unroll
            for (int q = 0; q < 8; ++q) u1[q] = f2bf((float)br[2 + (q >> 2)][q & 3]);
            Bs[wbase + ws0] = u0;
            Bs[wbase + ws1] = u1;
        }
        __syncthreads();

        if (kt + 1 < KDIM / 32) {
            const float* Xn = Xp + (size_t)(kt + 1) * 32;
            const int*   Wn = Wp + (size_t)(kt + 1) * 32;
            #pragma unroll
            for (int p = 0; p < 4; ++p) {
                ar[p] = *(const f32x4*)(Xn + p * 4);
                br[p] = *(const i32x4*)(Wn + p * 4);
            }
        }

        s16x8 af[4], bq[4];
        #pragma unroll
        for (int i = 0; i < 4; ++i) {
            int row = wr * 64 + i * 16 + fr;
            af[i] = As[row * 4 + (fs ^ ((row >> 1) & 3))];
        }
        #pragma unroll
        for (int j = 0; j < 4; ++j) {
            int col = wc * 64 + j * 16 + fr;
            bq[j] = Bs[col * 4 + (fs ^ ((col >> 1) & 3))];
        }
        #pragma unroll
        for (int i = 0; i < 4; ++i)
            #pragma unroll
            for (int j = 0; j < 4; ++j)
                acc[i][j] = __builtin_amdgcn_mfma_f32_16x16x32_bf16(
                    af[i], bq[j], acc[i][j], 0, 0, 0);
    }

    const float scale = scale_p[0];
    #pragma unroll
    for (int j = 0; j < 4; ++j) {
        const int c  = n0 + wc * 64 + j * 16 + fr;
        const float bj = bias[c];
        #pragma unroll
        for (int i = 0; i < 4; ++i) {
            const int r0 = m0 + wr * 64 + i * 16 + fs * 4;
            float* op = Out + (size_t)r0 * NDIM + c;
            #pragma unroll
            for (int q = 0; q < 4; ++q)
                op[(size_t)q * NDIM] = acc[i][j][q] * scale + bj;
        }
    }
}

extern "C" void kernel_launch(void* const* d_in, const int* in_sizes, int n_in,
                              void* d_out, int out_size, void* d_ws, size_t ws_size,
                              hipStream_t stream) {
    const float* X     = (const float*)d_in[0];
    const int*   Wq    = (const int*)d_in[1];   // int8 widened to int32 by harness
    const float* scale = (const float*)d_in[2];
    const float* bias  = (const float*)d_in[3];
    float*       Out   = (float*)d_out;

    const size_t xBytes = (size_t)MDIM * KDIM * 2;          // 67 MB
    const size_t wBytes = (size_t)NDIM * KDIM * 2;          // 134 MB
    if (ws_size >= xBytes + wBytes) {
        ushort_t* Xbf = (ushort_t*)d_ws;
        ushort_t* Wbf = (ushort_t*)((char*)d_ws + xBytes);
        hipLaunchKernelGGL(cvt_f32_bf16, dim3(2048), dim3(256), 0, stream,
                           X, Xbf, MDIM * KDIM / 8);
        hipLaunchKernelGGL(cvt_i32_bf16, dim3(2048), dim3(256), 0, stream,
                           Wq, Wbf, NDIM * KDIM / 8);
        hipLaunchKernelGGL(sl_gemm_256r, dim3(2048), dim3(512), 0, stream,
                           Xbf, Wbf, scale, bias, Out);
    } else {
        hipLaunchKernelGGL(sl_gemm_fb, dim3(8192), dim3(256), 0, stream,
                           X, Wq, scale, bias, Out);
    }
}